// Round 1
// baseline (479.508 us; speedup 1.0000x reference)
//
#include <hip/hip_runtime.h>
#include <hip/hip_bf16.h>
#include <math.h>

// Problem constants (fixed by setup_inputs)
constexpr int B = 4;
constexpr int L = 2048;
constexpr int H = 8;
constexpr int D = 64;
constexpr int S = 40;   // sample_k
constexpr int U = 40;   // top-u queries
constexpr int C = 32;   // cumsum chunks
constexpr int CHUNK = L / C;  // 64

// ---------------------------------------------------------------------------
// K1: M[b,h,l] = max_s(q.k_samp) - sum_s(q.k_samp)/L
// one thread per (b,l,h)
// ---------------------------------------------------------------------------
__global__ void compute_M(const float* __restrict__ q,
                          const float* __restrict__ k,
                          const int*   __restrict__ samp,
                          float* __restrict__ M) {
    int t = blockIdx.x * blockDim.x + threadIdx.x;   // (b*L + l)*H + h
    if (t >= B * L * H) return;
    int h  = t % H;
    int bl = t / H;
    int l  = bl % L;
    int b  = bl / L;

    const float4* qr = (const float4*)(q + ((size_t)(b * L + l) * H + h) * D);
    float4 qv[D / 4];
#pragma unroll
    for (int i = 0; i < D / 4; i++) qv[i] = qr[i];

    float maxv = -INFINITY, sumv = 0.f;
    for (int s = 0; s < S; s++) {
        int idx = samp[l * S + s];
        const float4* kr = (const float4*)(k + ((size_t)(b * L + idx) * H + h) * D);
        float acc = 0.f;
#pragma unroll
        for (int i = 0; i < D / 4; i++) {
            float4 kv = kr[i];
            acc += qv[i].x * kv.x + qv[i].y * kv.y + qv[i].z * kv.z + qv[i].w * kv.w;
        }
        maxv = fmaxf(maxv, acc);
        sumv += acc;
    }
    M[(size_t)(b * H + h) * L + l] = maxv - sumv * (1.0f / (float)L);
}

// ---------------------------------------------------------------------------
// K2: top-U indices of M per (b,h) row, tie -> lowest index (lax.top_k order)
// one block (256 thr) per (b,h)
// ---------------------------------------------------------------------------
__global__ void topk_M(const float* __restrict__ M, int* __restrict__ Mtop) {
    int bh = blockIdx.x;
    __shared__ float vals[L];
    __shared__ float rv[256];
    __shared__ int   ri[256];
    int tid = threadIdx.x;

    for (int i = tid; i < L; i += 256) vals[i] = M[(size_t)bh * L + i];
    __syncthreads();

    for (int it = 0; it < U; it++) {
        float best = -INFINITY;
        int   bi   = L;  // sentinel
        for (int i = tid; i < L; i += 256) {
            float v = vals[i];
            if (v > best || (v == best && i < bi)) { best = v; bi = i; }
        }
        rv[tid] = best; ri[tid] = bi;
        __syncthreads();
        for (int off = 128; off > 0; off >>= 1) {
            if (tid < off) {
                float v2 = rv[tid + off]; int i2 = ri[tid + off];
                if (v2 > rv[tid] || (v2 == rv[tid] && i2 < ri[tid])) {
                    rv[tid] = v2; ri[tid] = i2;
                }
            }
            __syncthreads();
        }
        if (tid == 0) {
            Mtop[bh * U + it] = ri[0];
            vals[ri[0]] = -INFINITY;
        }
        __syncthreads();
    }
}

// ---------------------------------------------------------------------------
// K3a: per-chunk sums of v along L.  block = (b,h,c), 64 threads (lane = d)
// ---------------------------------------------------------------------------
__global__ void cumsum_part(const float* __restrict__ v, float* __restrict__ part) {
    int blk = blockIdx.x;          // (b*H+h)*C + c
    int c  = blk % C;
    int bh = blk / C;
    int h  = bh % H;
    int b  = bh / H;
    int d  = threadIdx.x;

    const float* base = v + ((size_t)(b * L + c * CHUNK) * H + h) * D + d;
    float s = 0.f;
    for (int i = 0; i < CHUNK; i++) s += base[(size_t)i * H * D];
    part[(size_t)blk * D + d] = s;
}

// ---------------------------------------------------------------------------
// K3b: prefix of chunk partials + in-chunk scan, write full output
// ---------------------------------------------------------------------------
__global__ void cumsum_write(const float* __restrict__ v,
                             const float* __restrict__ part,
                             float* __restrict__ out) {
    int blk = blockIdx.x;
    int c  = blk % C;
    int bh = blk / C;
    int h  = bh % H;
    int b  = bh / H;
    int d  = threadIdx.x;

    float run = 0.f;
    for (int cc = 0; cc < c; cc++) run += part[((size_t)bh * C + cc) * D + d];

    const float* base  = v   + ((size_t)(b * L + c * CHUNK) * H + h) * D + d;
    float*       obase = out + ((size_t)(b * L + c * CHUNK) * H + h) * D + d;
    for (int i = 0; i < CHUNK; i++) {
        run += base[(size_t)i * H * D];
        obase[(size_t)i * H * D] = run;
    }
}

// ---------------------------------------------------------------------------
// K5: causal softmax attention for each selected query; overwrite out row.
// block = (b,h,u), 256 threads (4 waves)
// ---------------------------------------------------------------------------
__global__ void attn_update(const float* __restrict__ q,
                            const float* __restrict__ k,
                            const float* __restrict__ v,
                            const int*   __restrict__ Mtop,
                            float* __restrict__ out) {
    int blk = blockIdx.x;          // (b*H+h)*U + u
    int u  = blk % U;
    int bh = blk / U;
    int h  = bh % H;
    int b  = bh / H;
    int qi = Mtop[bh * U + u];
    int nk = qi + 1;               // keys j <= qi are unmasked

    __shared__ float qs[D];
    __shared__ float sc[L];
    __shared__ float red[256];
    __shared__ float accs[4][D];

    int tid  = threadIdx.x;
    int lane = tid & 63;
    int wav  = tid >> 6;

    if (tid < D) qs[tid] = q[((size_t)(b * L + qi) * H + h) * D + tid];
    __syncthreads();

    // scores: 16 lanes cooperate per key (float4 each), 16 keys per block-iter
    int g  = lane >> 4;   // key sub-slot within wave (0..3)
    int d4 = lane & 15;   // float4 index within row
    float4 qv = ((const float4*)qs)[d4];
    for (int base = 0; base < nk; base += 16) {
        int j = base + wav * 4 + g;
        float p = 0.f;
        if (j < nk) {
            const float4* kr = (const float4*)(k + ((size_t)(b * L + j) * H + h) * D);
            float4 kv = kr[d4];
            p = qv.x * kv.x + qv.y * kv.y + qv.z * kv.z + qv.w * kv.w;
        }
        p += __shfl_xor(p, 1);
        p += __shfl_xor(p, 2);
        p += __shfl_xor(p, 4);
        p += __shfl_xor(p, 8);
        if (d4 == 0 && j < nk) sc[j] = p * 0.125f;   // 1/sqrt(64)
    }
    __syncthreads();

    // row max
    float m = -INFINITY;
    for (int j = tid; j < nk; j += 256) m = fmaxf(m, sc[j]);
    red[tid] = m;
    __syncthreads();
    for (int off = 128; off > 0; off >>= 1) {
        if (tid < off) red[tid] = fmaxf(red[tid], red[tid + off]);
        __syncthreads();
    }
    m = red[0];
    __syncthreads();

    // exp + sum
    float s = 0.f;
    for (int j = tid; j < nk; j += 256) {
        float e = __expf(sc[j] - m);
        sc[j] = e;
        s += e;
    }
    red[tid] = s;
    __syncthreads();
    for (int off = 128; off > 0; off >>= 1) {
        if (tid < off) red[tid] += red[tid + off];
        __syncthreads();
    }
    float inv = 1.0f / red[0];

    // ctx[d] = sum_j p_j * v[j][d]; wave w takes j = w, w+4, ... (coalesced in d)
    float acc = 0.f;
    for (int j = wav; j < nk; j += 4) {
        acc += sc[j] * v[((size_t)(b * L + j) * H + h) * D + lane];
    }
    accs[wav][lane] = acc;
    __syncthreads();
    if (wav == 0) {
        float r = accs[0][lane] + accs[1][lane] + accs[2][lane] + accs[3][lane];
        out[((size_t)(b * L + qi) * H + h) * D + lane] = r * inv;
    }
}

// ---------------------------------------------------------------------------
extern "C" void kernel_launch(void* const* d_in, const int* in_sizes, int n_in,
                              void* d_out, int out_size, void* d_ws, size_t ws_size,
                              hipStream_t stream) {
    const float* q    = (const float*)d_in[0];
    const float* k    = (const float*)d_in[1];
    const float* v    = (const float*)d_in[2];
    const int*   samp = (const int*)d_in[3];
    float* out = (float*)d_out;

    // workspace layout
    float* M    = (float*)d_ws;                 // B*H*L floats
    int*   Mtop = (int*)(M + (size_t)B * H * L);      // B*H*U ints
    float* part = (float*)(Mtop + (size_t)B * H * U); // B*H*C*D floats

    compute_M<<<(B * L * H + 255) / 256, 256, 0, stream>>>(q, k, samp, M);
    topk_M<<<B * H, 256, 0, stream>>>(M, Mtop);
    cumsum_part<<<B * H * C, 64, 0, stream>>>(v, part);
    cumsum_write<<<B * H * C, 64, 0, stream>>>(v, part, out);
    attn_update<<<B * H * U, 256, 0, stream>>>(q, k, v, Mtop, out);
}

// Round 2
// 370.345 us; speedup vs baseline: 1.2948x; 1.2948x over previous
//
#include <hip/hip_runtime.h>
#include <hip/hip_bf16.h>
#include <math.h>

// Problem constants (fixed by setup_inputs)
constexpr int B = 4;
constexpr int L = 2048;
constexpr int H = 8;
constexpr int D = 64;
constexpr int S = 40;   // sample_k
constexpr int U = 40;   // top-u queries
constexpr int C = 32;   // cumsum chunks
constexpr int CHUNK = L / C;  // 64
constexpr int NSEG = 8;       // key segments for attention
constexpr int SEG  = L / NSEG; // 256

// ---------------------------------------------------------------------------
// K1: M[b,h,l] = max_s(q.k_samp) - sum_s(q.k_samp)/L
// block = (b,l), 256 threads = 8 h-groups x 32 lanes (float2 per lane).
// samp index is block-uniform -> scalar load; each k-row read is a fully
// coalesced 2 KB block read.
// ---------------------------------------------------------------------------
__global__ void compute_M(const float* __restrict__ q,
                          const float* __restrict__ k,
                          const int*   __restrict__ samp,
                          float* __restrict__ M) {
    int blk = blockIdx.x;            // b*L + l
    int l = blk % L;
    int b = blk / L;
    int tid = threadIdx.x;
    int h  = tid >> 5;               // 0..7
    int dd = tid & 31;               // float2 slot

    const float2* q2 = (const float2*)(q + ((size_t)(b * L + l) * H + h) * D);
    float2 qv = q2[dd];

    float maxv = -INFINITY, sumv = 0.f;
#pragma unroll 4
    for (int s = 0; s < S; s++) {
        int idx = samp[l * S + s];   // uniform across block -> s_load
        const float2* k2 = (const float2*)(k + ((size_t)(b * L + idx) * H + h) * D);
        float2 kv = k2[dd];
        float p = qv.x * kv.x + qv.y * kv.y;
        p += __shfl_xor(p, 1);
        p += __shfl_xor(p, 2);
        p += __shfl_xor(p, 4);
        p += __shfl_xor(p, 8);
        p += __shfl_xor(p, 16);      // all 32 lanes of the h-group now hold the dot
        maxv = fmaxf(maxv, p);
        sumv += p;
    }
    if (dd == 0) M[(size_t)(b * H + h) * L + l] = maxv - sumv * (1.0f / (float)L);
}

// ---------------------------------------------------------------------------
// K2: top-U indices of M per (b,h) row, tie -> lowest index (lax.top_k order)
// one block (256 thr) per (b,h)
// ---------------------------------------------------------------------------
__global__ void topk_M(const float* __restrict__ M, int* __restrict__ Mtop) {
    int bh = blockIdx.x;
    __shared__ float vals[L];
    __shared__ float rv[256];
    __shared__ int   ri[256];
    int tid = threadIdx.x;

    for (int i = tid; i < L; i += 256) vals[i] = M[(size_t)bh * L + i];
    __syncthreads();

    for (int it = 0; it < U; it++) {
        float best = -INFINITY;
        int   bi   = L;  // sentinel
        for (int i = tid; i < L; i += 256) {
            float v = vals[i];
            if (v > best || (v == best && i < bi)) { best = v; bi = i; }
        }
        rv[tid] = best; ri[tid] = bi;
        __syncthreads();
        for (int off = 128; off > 0; off >>= 1) {
            if (tid < off) {
                float v2 = rv[tid + off]; int i2 = ri[tid + off];
                if (v2 > rv[tid] || (v2 == rv[tid] && i2 < ri[tid])) {
                    rv[tid] = v2; ri[tid] = i2;
                }
            }
            __syncthreads();
        }
        if (tid == 0) {
            Mtop[bh * U + it] = ri[0];
            vals[ri[0]] = -INFINITY;
        }
        __syncthreads();
    }
}

// ---------------------------------------------------------------------------
// K3a: per-chunk sums of v along L.  block = (b,h,c), 64 threads (lane = d)
// ---------------------------------------------------------------------------
__global__ void cumsum_part(const float* __restrict__ v, float* __restrict__ part) {
    int blk = blockIdx.x;          // (b*H+h)*C + c
    int c  = blk % C;
    int bh = blk / C;
    int h  = bh % H;
    int b  = bh / H;
    int d  = threadIdx.x;

    const float* base = v + ((size_t)(b * L + c * CHUNK) * H + h) * D + d;
    float s = 0.f;
    for (int i = 0; i < CHUNK; i++) s += base[(size_t)i * H * D];
    part[(size_t)blk * D + d] = s;
}

// ---------------------------------------------------------------------------
// K3b: prefix of chunk partials + in-chunk scan, write full output
// ---------------------------------------------------------------------------
__global__ void cumsum_write(const float* __restrict__ v,
                             const float* __restrict__ part,
                             float* __restrict__ out) {
    int blk = blockIdx.x;
    int c  = blk % C;
    int bh = blk / C;
    int h  = bh % H;
    int b  = bh / H;
    int d  = threadIdx.x;

    float run = 0.f;
    for (int cc = 0; cc < c; cc++) run += part[((size_t)bh * C + cc) * D + d];

    const float* base  = v   + ((size_t)(b * L + c * CHUNK) * H + h) * D + d;
    float*       obase = out + ((size_t)(b * L + c * CHUNK) * H + h) * D + d;
    for (int i = 0; i < CHUNK; i++) {
        run += base[(size_t)i * H * D];
        obase[(size_t)i * H * D] = run;
    }
}

// ---------------------------------------------------------------------------
// K5a: segmented online-softmax partials.
// block = (b,h,u,seg), 256 threads; segment covers SEG keys.
// Writes {m, l} to ml[] and unnormalized acc[64] to pacc[].
// ---------------------------------------------------------------------------
__global__ void attn_partial(const float* __restrict__ q,
                             const float* __restrict__ k,
                             const float* __restrict__ v,
                             const int*   __restrict__ Mtop,
                             float* __restrict__ ml,
                             float* __restrict__ pacc) {
    int blk = blockIdx.x;          // ((bh*U)+u)*NSEG + seg
    int seg  = blk & (NSEG - 1);
    int rest = blk / NSEG;
    int u  = rest % U;
    int bh = rest / U;
    int h  = bh % H;
    int b  = bh / H;
    int tid  = threadIdx.x;
    int lane = tid & 63;
    int wav  = tid >> 6;

    int qi = Mtop[bh * U + u];
    int j0 = seg * SEG;
    int nk = qi + 1 - j0;          // valid keys in this segment
    if (nk <= 0) {
        // must still produce a well-defined (empty) record: ws is poisoned.
        if (tid < D) pacc[(size_t)blk * D + tid] = 0.f;
        if (tid == 0) { ml[2 * (size_t)blk] = -INFINITY; ml[2 * (size_t)blk + 1] = 0.f; }
        return;
    }
    if (nk > SEG) nk = SEG;

    __shared__ float qs[D];
    __shared__ float sc[SEG];
    __shared__ float red[256];
    __shared__ float accs[4][D];

    if (tid < D) qs[tid] = q[((size_t)(b * L + qi) * H + h) * D + tid];
    sc[tid] = -INFINITY;
    __syncthreads();

    // scores: 16 lanes per key (float4 each); 16 keys per block-iteration
    int g  = lane >> 4;   // key sub-slot within wave (0..3)
    int d4 = lane & 15;   // float4 index within row
    float4 qv = ((const float4*)qs)[d4];
    for (int base = 0; base < nk; base += 16) {
        int jl = base + wav * 4 + g;
        if (jl < nk) {
            const float4* kr = (const float4*)(k + ((size_t)(b * L + j0 + jl) * H + h) * D);
            float4 kv = kr[d4];
            float p = qv.x * kv.x + qv.y * kv.y + qv.z * kv.z + qv.w * kv.w;
            p += __shfl_xor(p, 1);
            p += __shfl_xor(p, 2);
            p += __shfl_xor(p, 4);
            p += __shfl_xor(p, 8);
            if (d4 == 0) sc[jl] = p * 0.125f;   // 1/sqrt(64)
        }
    }
    __syncthreads();

    // segment max
    float m = sc[tid];
    red[tid] = m;
    __syncthreads();
    for (int off = 128; off > 0; off >>= 1) {
        if (tid < off) red[tid] = fmaxf(red[tid], red[tid + off]);
        __syncthreads();
    }
    m = red[0];
    __syncthreads();

    // exp + sum (invalid slots hold -inf -> exp -> 0)
    float e = __expf(sc[tid] - m);
    sc[tid] = e;
    red[tid] = e;
    __syncthreads();
    for (int off = 128; off > 0; off >>= 1) {
        if (tid < off) red[tid] += red[tid + off];
        __syncthreads();
    }
    float lsum = red[0];

    // PV: wave w accumulates keys jl = w, w+4, ... (coalesced in d = lane)
    float acc = 0.f;
    for (int jl = wav; jl < nk; jl += 4) {
        acc += sc[jl] * v[((size_t)(b * L + j0 + jl) * H + h) * D + lane];
    }
    accs[wav][lane] = acc;
    __syncthreads();
    if (wav == 0) {
        float r = accs[0][lane] + accs[1][lane] + accs[2][lane] + accs[3][lane];
        pacc[(size_t)blk * D + lane] = r;
    }
    if (tid == 0) { ml[2 * (size_t)blk] = m; ml[2 * (size_t)blk + 1] = lsum; }
}

// ---------------------------------------------------------------------------
// K5b: combine NSEG partials per (b,h,u), write the output row.
// block = (b,h,u), 64 threads (lane = d)
// ---------------------------------------------------------------------------
__global__ void attn_combine(const int* __restrict__ Mtop,
                             const float* __restrict__ ml,
                             const float* __restrict__ pacc,
                             float* __restrict__ out) {
    int blk = blockIdx.x;          // bh*U + u
    int u  = blk % U;
    int bh = blk / U;
    int h  = bh % H;
    int b  = bh / H;
    int d  = threadIdx.x;
    int qi = Mtop[bh * U + u];

    size_t r0 = (size_t)blk * NSEG;
    float m = -INFINITY;
#pragma unroll
    for (int s = 0; s < NSEG; s++) m = fmaxf(m, ml[2 * (r0 + s)]);

    float lt = 0.f, acc = 0.f;
#pragma unroll
    for (int s = 0; s < NSEG; s++) {
        float ms = ml[2 * (r0 + s)];
        float w  = __expf(ms - m);          // -inf -> 0 (m finite: seg 0 valid)
        lt  += ml[2 * (r0 + s) + 1] * w;
        acc += pacc[(r0 + s) * D + d] * w;
    }
    out[((size_t)(b * L + qi) * H + h) * D + d] = acc / lt;
}

// ---------------------------------------------------------------------------
extern "C" void kernel_launch(void* const* d_in, const int* in_sizes, int n_in,
                              void* d_out, int out_size, void* d_ws, size_t ws_size,
                              hipStream_t stream) {
    const float* q    = (const float*)d_in[0];
    const float* k    = (const float*)d_in[1];
    const float* v    = (const float*)d_in[2];
    const int*   samp = (const int*)d_in[3];
    float* out = (float*)d_out;

    // workspace layout
    float* M    = (float*)d_ws;                        // B*H*L floats
    int*   Mtop = (int*)(M + (size_t)B * H * L);       // B*H*U ints
    float* part = (float*)(Mtop + (size_t)B * H * U);  // B*H*C*D floats
    float* ml   = part + (size_t)B * H * C * D;        // B*H*U*NSEG*2 floats
    float* pacc = ml + (size_t)B * H * U * NSEG * 2;   // B*H*U*NSEG*D floats

    compute_M<<<B * L, 256, 0, stream>>>(q, k, samp, M);
    topk_M<<<B * H, 256, 0, stream>>>(M, Mtop);
    cumsum_part<<<B * H * C, 64, 0, stream>>>(v, part);
    cumsum_write<<<B * H * C, 64, 0, stream>>>(v, part, out);
    attn_partial<<<B * H * U * NSEG, 256, 0, stream>>>(q, k, v, Mtop, ml, pacc);
    attn_combine<<<B * H * U, 64, 0, stream>>>(Mtop, ml, pacc, out);
}

// Round 3
// 266.732 us; speedup vs baseline: 1.7977x; 1.3885x over previous
//
#include <hip/hip_runtime.h>
#include <hip/hip_bf16.h>
#include <math.h>

// Problem constants (fixed by setup_inputs)
constexpr int B = 4;
constexpr int L = 2048;
constexpr int H = 8;
constexpr int D = 64;
constexpr int S = 40;   // sample_k
constexpr int U = 40;   // top-u queries
constexpr int C = 32;   // cumsum chunks
constexpr int CHUNK = L / C;  // 64
constexpr int NSEG = 8;       // key segments for attention
constexpr int SEG  = L / NSEG; // 256

// ---------------------------------------------------------------------------
// K1: M[b,h,l] = max_s(q.k_samp) - sum_s(q.k_samp)/L
// block = (b,l), 256 threads = 8 h-groups x 32 lanes (float2 per lane).
// Phase A: per-sample per-lane partial dots -> LDS (XOR-swizzled, no shfl
// chains, loads fully pipelined). Phase B: thread-per-sample serial sum
// (conflict-free banks), then ONE 5-shfl max/sum reduce per (h).
// ---------------------------------------------------------------------------
__global__ void compute_M(const float* __restrict__ q,
                          const float* __restrict__ k,
                          const int*   __restrict__ samp,
                          float* __restrict__ M) {
    __shared__ float pa[H * S * 32];   // 8*40*32 floats = 40 KB
    int blk = blockIdx.x;              // b*L + l
    int l = blk % L;
    int b = blk / L;
    int tid = threadIdx.x;
    int h      = tid >> 5;             // 0..7
    int lane32 = tid & 31;

    const float2* q2 = (const float2*)(q + ((size_t)(b * L + l) * H + h) * D);
    float2 qv = q2[lane32];

    const int* srow = samp + l * S;
    float* pah = pa + h * (S * 32);
#pragma unroll 4
    for (int s = 0; s < S; s++) {
        int idx = srow[s];             // block-uniform -> scalar load
        const float2* k2 = (const float2*)(k + ((size_t)(b * L + idx) * H + h) * D);
        float2 kv = k2[lane32];
        // XOR swizzle: column = lane32 ^ (s&31) -> conflict-free writes & reads
        pah[s * 32 + (lane32 ^ (s & 31))] = qv.x * kv.x + qv.y * kv.y;
    }
    __syncthreads();

    // Phase B: lane s sums sample s's 32 partials (and sample s+32 if s<8)
    int s1 = lane32;
    float a0 = 0.f, a1 = 0.f, a2 = 0.f, a3 = 0.f;
#pragma unroll
    for (int i = 0; i < 32; i += 4) {
        a0 += pah[s1 * 32 + ((i + 0) ^ s1)];
        a1 += pah[s1 * 32 + ((i + 1) ^ s1)];
        a2 += pah[s1 * 32 + ((i + 2) ^ s1)];
        a3 += pah[s1 * 32 + ((i + 3) ^ s1)];
    }
    float dot1 = (a0 + a1) + (a2 + a3);
    float mv = dot1, sv = dot1;
    if (lane32 < S - 32) {             // second sample s2 = 32 + lane32
        int s2 = lane32 + 32;
        int sm = s2 & 31;              // == lane32
        float b0 = 0.f, b1 = 0.f, b2 = 0.f, b3 = 0.f;
#pragma unroll
        for (int i = 0; i < 32; i += 4) {
            b0 += pah[s2 * 32 + ((i + 0) ^ sm)];
            b1 += pah[s2 * 32 + ((i + 1) ^ sm)];
            b2 += pah[s2 * 32 + ((i + 2) ^ sm)];
            b3 += pah[s2 * 32 + ((i + 3) ^ sm)];
        }
        float dot2 = (b0 + b1) + (b2 + b3);
        mv = fmaxf(mv, dot2);
        sv += dot2;
    }
    // ONE cross-lane reduce over the 32-lane h-group (offsets stay in-half)
#pragma unroll
    for (int off = 1; off <= 16; off <<= 1) {
        mv = fmaxf(mv, __shfl_xor(mv, off));
        sv += __shfl_xor(sv, off);
    }
    if (lane32 == 0) M[(size_t)(b * H + h) * L + l] = mv - sv * (1.0f / (float)L);
}

// ---------------------------------------------------------------------------
// K2: top-U indices of M per (b,h), tie -> lowest index (lax.top_k order).
// Register-resident: 8 values/thread; per iter: local argmax + 6-shfl wave
// argmax + tiny LDS combine (2 barriers), then owner kills its register copy.
// ---------------------------------------------------------------------------
__global__ void topk_M(const float* __restrict__ M, int* __restrict__ Mtop) {
    int bh  = blockIdx.x;
    int tid = threadIdx.x;
    const float4* row4 = (const float4*)(M + (size_t)bh * L);
    float4 v0 = row4[tid * 2];
    float4 v1 = row4[tid * 2 + 1];
    float vals[8] = {v0.x, v0.y, v0.z, v0.w, v1.x, v1.y, v1.z, v1.w};
    int base = tid * 8;

    __shared__ float wv[4];
    __shared__ int   wi[4];
    __shared__ int   bidx;

    for (int it = 0; it < U; it++) {
        // local argmax (ascending idx: strict > keeps lowest index on ties)
        float bv = vals[0];
        int   bi = base;
#pragma unroll
        for (int r = 1; r < 8; r++) {
            if (vals[r] > bv) { bv = vals[r]; bi = base + r; }
        }
        // wave argmax
#pragma unroll
        for (int off = 1; off <= 32; off <<= 1) {
            float ov = __shfl_xor(bv, off);
            int   oi = __shfl_xor(bi, off);
            if (ov > bv || (ov == bv && oi < bi)) { bv = ov; bi = oi; }
        }
        int w = tid >> 6;
        if ((tid & 63) == 0) { wv[w] = bv; wi[w] = bi; }
        __syncthreads();
        if (tid == 0) {
            float Bv = wv[0]; int Bi = wi[0];
#pragma unroll
            for (int ww = 1; ww < 4; ww++) {
                if (wv[ww] > Bv || (wv[ww] == Bv && wi[ww] < Bi)) { Bv = wv[ww]; Bi = wi[ww]; }
            }
            Mtop[bh * U + it] = Bi;
            bidx = Bi;
        }
        __syncthreads();
        int kb = bidx;
#pragma unroll
        for (int r = 0; r < 8; r++) {
            if (base + r == kb) vals[r] = -INFINITY;
        }
    }
}

// ---------------------------------------------------------------------------
// K3a: per-chunk sums of v along L.  block = (b,h,c), 64 threads (lane = d)
// ---------------------------------------------------------------------------
__global__ void cumsum_part(const float* __restrict__ v, float* __restrict__ part) {
    int blk = blockIdx.x;          // (b*H+h)*C + c
    int c  = blk % C;
    int bh = blk / C;
    int h  = bh % H;
    int b  = bh / H;
    int d  = threadIdx.x;

    const float* base = v + ((size_t)(b * L + c * CHUNK) * H + h) * D + d;
    float s = 0.f;
    for (int i = 0; i < CHUNK; i++) s += base[(size_t)i * H * D];
    part[(size_t)blk * D + d] = s;
}

// ---------------------------------------------------------------------------
// K3b: prefix of chunk partials + in-chunk scan, write full output
// ---------------------------------------------------------------------------
__global__ void cumsum_write(const float* __restrict__ v,
                             const float* __restrict__ part,
                             float* __restrict__ out) {
    int blk = blockIdx.x;
    int c  = blk % C;
    int bh = blk / C;
    int h  = bh % H;
    int b  = bh / H;
    int d  = threadIdx.x;

    float run = 0.f;
    for (int cc = 0; cc < c; cc++) run += part[((size_t)bh * C + cc) * D + d];

    const float* base  = v   + ((size_t)(b * L + c * CHUNK) * H + h) * D + d;
    float*       obase = out + ((size_t)(b * L + c * CHUNK) * H + h) * D + d;
    for (int i = 0; i < CHUNK; i++) {
        run += base[(size_t)i * H * D];
        obase[(size_t)i * H * D] = run;
    }
}

// ---------------------------------------------------------------------------
// K5a: segmented softmax partials, latency-lean version.
// block = (b,h,u,seg), 256 threads; wave w owns keys [64w, 64w+64).
// Per-thread online max during scores; ONE wave shfl-max + ONE wave shfl-sum;
// exp computed once per slot; PV with e-broadcast from LDS, 2 accumulators.
// ---------------------------------------------------------------------------
__global__ void attn_partial(const float* __restrict__ q,
                             const float* __restrict__ k,
                             const float* __restrict__ v,
                             const int*   __restrict__ Mtop,
                             float* __restrict__ ml,
                             float* __restrict__ pacc) {
    int blk = blockIdx.x;          // ((bh*U)+u)*NSEG + seg
    int seg  = blk & (NSEG - 1);
    int rest = blk / NSEG;
    int u  = rest % U;
    int bh = rest / U;
    int h  = bh % H;
    int b  = bh / H;
    int tid  = threadIdx.x;
    int lane = tid & 63;
    int wav  = tid >> 6;

    int qi = Mtop[bh * U + u];
    int j0 = seg * SEG;
    int nk = qi + 1 - j0;          // valid keys in this segment
    if (nk <= 0) {                 // empty segment: well-defined record (ws poisoned)
        if (tid < D) pacc[(size_t)blk * D + tid] = 0.f;
        if (tid == 0) { ml[2 * (size_t)blk] = -INFINITY; ml[2 * (size_t)blk + 1] = 0.f; }
        return;
    }
    if (nk > SEG) nk = SEG;

    __shared__ float qs[D];
    __shared__ float sc[SEG];
    __shared__ float wredm[4];
    __shared__ float wrede[4];
    __shared__ float accs[4][D];

    if (tid < D) qs[tid] = q[((size_t)(b * L + qi) * H + h) * D + tid];
    sc[tid] = -INFINITY;
    __syncthreads();

    // ---- scores: wave w covers its own 64 keys; 16 lanes per key ----
    int g  = lane >> 4;   // key sub-slot (0..3)
    int d4 = lane & 15;   // float4 index within row
    float4 qv = ((const float4*)qs)[d4];
    int wbase = wav * 64;
    float m_t = -INFINITY;
    const float* kbase = k + ((size_t)(b * L + j0) * H + h) * D;
#pragma unroll 4
    for (int t = 0; t < 16; t++) {
        int jl = wbase + t * 4 + g;
        if (jl < nk) {
            const float4* kr = (const float4*)(kbase + (size_t)jl * (H * D));
            float4 kv = kr[d4];
            float p = qv.x * kv.x + qv.y * kv.y + qv.z * kv.z + qv.w * kv.w;
            p += __shfl_xor(p, 1);
            p += __shfl_xor(p, 2);
            p += __shfl_xor(p, 4);
            p += __shfl_xor(p, 8);
            p *= 0.125f;           // 1/sqrt(64)
            if (d4 == 0) sc[jl] = p;
            m_t = fmaxf(m_t, p);
        }
    }
    // block max: one wave shfl reduce + tiny LDS combine
#pragma unroll
    for (int off = 1; off <= 32; off <<= 1) m_t = fmaxf(m_t, __shfl_xor(m_t, off));
    if (lane == 0) wredm[wav] = m_t;
    __syncthreads();
    float m = fmaxf(fmaxf(wredm[0], wredm[1]), fmaxf(wredm[2], wredm[3]));

    // exp once per slot (masked slots: -inf -> 0), block sum likewise
    float e = __expf(sc[tid] - m);
    sc[tid] = e;
    float l_t = e;
#pragma unroll
    for (int off = 1; off <= 32; off <<= 1) l_t += __shfl_xor(l_t, off);
    if (lane == 0) wrede[wav] = l_t;
    __syncthreads();               // also publishes sc[]=e for PV
    float lsum = (wrede[0] + wrede[1]) + (wrede[2] + wrede[3]);

    // ---- PV: wave w sums its 64 keys; lane = d; e broadcast from LDS ----
    float acc0 = 0.f, acc1 = 0.f;
    int cnt = nk - wbase;
    if (cnt < 0) cnt = 0;
    if (cnt > 64) cnt = 64;
    const float* vbase = v + ((size_t)(b * L + j0 + wbase) * H + h) * D + lane;
#pragma unroll 2
    for (int i = 0; i + 2 <= cnt; i += 2) {
        acc0 += sc[wbase + i]     * vbase[(size_t)(i)     * (H * D)];
        acc1 += sc[wbase + i + 1] * vbase[(size_t)(i + 1) * (H * D)];
    }
    if (cnt & 1) acc0 += sc[wbase + cnt - 1] * vbase[(size_t)(cnt - 1) * (H * D)];

    accs[wav][lane] = acc0 + acc1;
    __syncthreads();
    if (wav == 0) {
        float r = accs[0][lane] + accs[1][lane] + accs[2][lane] + accs[3][lane];
        pacc[(size_t)blk * D + lane] = r;
    }
    if (tid == 0) { ml[2 * (size_t)blk] = m; ml[2 * (size_t)blk + 1] = lsum; }
}

// ---------------------------------------------------------------------------
// K5b: combine NSEG partials per (b,h,u), write the output row.
// block = (b,h,u), 64 threads (lane = d)
// ---------------------------------------------------------------------------
__global__ void attn_combine(const int* __restrict__ Mtop,
                             const float* __restrict__ ml,
                             const float* __restrict__ pacc,
                             float* __restrict__ out) {
    int blk = blockIdx.x;          // bh*U + u
    int u  = blk % U;
    int bh = blk / U;
    int h  = bh % H;
    int b  = bh / H;
    int d  = threadIdx.x;
    int qi = Mtop[bh * U + u];

    size_t r0 = (size_t)blk * NSEG;
    float m = -INFINITY;
#pragma unroll
    for (int s = 0; s < NSEG; s++) m = fmaxf(m, ml[2 * (r0 + s)]);

    float lt = 0.f, acc = 0.f;
#pragma unroll
    for (int s = 0; s < NSEG; s++) {
        float ms = ml[2 * (r0 + s)];
        float w  = __expf(ms - m);          // -inf -> 0 (m finite: seg 0 valid)
        lt  += ml[2 * (r0 + s) + 1] * w;
        acc += pacc[(r0 + s) * D + d] * w;
    }
    out[((size_t)(b * L + qi) * H + h) * D + d] = acc / lt;
}

// ---------------------------------------------------------------------------
extern "C" void kernel_launch(void* const* d_in, const int* in_sizes, int n_in,
                              void* d_out, int out_size, void* d_ws, size_t ws_size,
                              hipStream_t stream) {
    const float* q    = (const float*)d_in[0];
    const float* k    = (const float*)d_in[1];
    const float* v    = (const float*)d_in[2];
    const int*   samp = (const int*)d_in[3];
    float* out = (float*)d_out;

    // workspace layout
    float* M    = (float*)d_ws;                        // B*H*L floats
    int*   Mtop = (int*)(M + (size_t)B * H * L);       // B*H*U ints
    float* part = (float*)(Mtop + (size_t)B * H * U);  // B*H*C*D floats
    float* ml   = part + (size_t)B * H * C * D;        // B*H*U*NSEG*2 floats
    float* pacc = ml + (size_t)B * H * U * NSEG * 2;   // B*H*U*NSEG*D floats

    compute_M<<<B * L, 256, 0, stream>>>(q, k, samp, M);
    topk_M<<<B * H, 256, 0, stream>>>(M, Mtop);
    cumsum_part<<<B * H * C, 64, 0, stream>>>(v, part);
    cumsum_write<<<B * H * C, 64, 0, stream>>>(v, part, out);
    attn_partial<<<B * H * U * NSEG, 256, 0, stream>>>(q, k, v, Mtop, ml, pacc);
    attn_combine<<<B * H * U, 64, 0, stream>>>(Mtop, ml, pacc, out);
}

// Round 4
// 218.423 us; speedup vs baseline: 2.1953x; 1.2212x over previous
//
#include <hip/hip_runtime.h>
#include <hip/hip_bf16.h>
#include <math.h>

// Problem constants (fixed by setup_inputs)
constexpr int B = 4;
constexpr int L = 2048;
constexpr int H = 8;
constexpr int D = 64;
constexpr int S = 40;   // sample_k
constexpr int U = 40;   // top-u queries
constexpr int C = 32;   // cumsum chunks
constexpr int CHUNK = L / C;   // 64
constexpr int NSEG = 16;       // key segments for attention
constexpr int SEG  = L / NSEG; // 128

// ---------------------------------------------------------------------------
// K1: M[b,h,l] = max_s(q.k_samp) - sum_s(q.k_samp)/L
// block = (b,l) via XCD swizzle (batch b pinned to XCDs {2b,2b+1} so K[b]=4MB
// stays in those L2s). 256 threads = 8 h-groups x 32 lanes (float2 per lane).
// ---------------------------------------------------------------------------
__global__ void compute_M(const float* __restrict__ q,
                          const float* __restrict__ k,
                          const int*   __restrict__ samp,
                          float* __restrict__ M) {
    __shared__ float pa[H * S * 32];   // 8*40*32 floats = 40 KB
    int blk = blockIdx.x;              // [0, B*L)
    int xcd = blk & 7;
    int b   = xcd >> 1;
    int l   = ((blk >> 3) << 1) | (xcd & 1);
    int tid = threadIdx.x;
    int h      = tid >> 5;             // 0..7
    int lane32 = tid & 31;

    const float2* q2 = (const float2*)(q + ((size_t)(b * L + l) * H + h) * D);
    float2 qv = q2[lane32];

    const int* srow = samp + l * S;
    float* pah = pa + h * (S * 32);
#pragma unroll 4
    for (int s = 0; s < S; s++) {
        int idx = srow[s];             // block-uniform -> scalar load
        const float2* k2 = (const float2*)(k + ((size_t)(b * L + idx) * H + h) * D);
        float2 kv = k2[lane32];
        pah[s * 32 + (lane32 ^ (s & 31))] = qv.x * kv.x + qv.y * kv.y;
    }
    __syncthreads();

    int s1 = lane32;
    float a0 = 0.f, a1 = 0.f, a2 = 0.f, a3 = 0.f;
#pragma unroll
    for (int i = 0; i < 32; i += 4) {
        a0 += pah[s1 * 32 + ((i + 0) ^ s1)];
        a1 += pah[s1 * 32 + ((i + 1) ^ s1)];
        a2 += pah[s1 * 32 + ((i + 2) ^ s1)];
        a3 += pah[s1 * 32 + ((i + 3) ^ s1)];
    }
    float dot1 = (a0 + a1) + (a2 + a3);
    float mv = dot1, sv = dot1;
    if (lane32 < S - 32) {
        int s2 = lane32 + 32;
        int sm = s2 & 31;
        float b0 = 0.f, b1 = 0.f, b2 = 0.f, b3 = 0.f;
#pragma unroll
        for (int i = 0; i < 32; i += 4) {
            b0 += pah[s2 * 32 + ((i + 0) ^ sm)];
            b1 += pah[s2 * 32 + ((i + 1) ^ sm)];
            b2 += pah[s2 * 32 + ((i + 2) ^ sm)];
            b3 += pah[s2 * 32 + ((i + 3) ^ sm)];
        }
        float dot2 = (b0 + b1) + (b2 + b3);
        mv = fmaxf(mv, dot2);
        sv += dot2;
    }
#pragma unroll
    for (int off = 1; off <= 16; off <<= 1) {
        mv = fmaxf(mv, __shfl_xor(mv, off));
        sv += __shfl_xor(sv, off);
    }
    if (lane32 == 0) M[(size_t)(b * H + h) * L + l] = mv - sv * (1.0f / (float)L);
}

// ---------------------------------------------------------------------------
// K2: top-U indices of M per (b,h), tie -> lowest index (lax.top_k order).
// ---------------------------------------------------------------------------
__global__ void topk_M(const float* __restrict__ M, int* __restrict__ Mtop) {
    int bh  = blockIdx.x;
    int tid = threadIdx.x;
    const float4* row4 = (const float4*)(M + (size_t)bh * L);
    float4 v0 = row4[tid * 2];
    float4 v1 = row4[tid * 2 + 1];
    float vals[8] = {v0.x, v0.y, v0.z, v0.w, v1.x, v1.y, v1.z, v1.w};
    int base = tid * 8;

    __shared__ float wv[4];
    __shared__ int   wi[4];
    __shared__ int   bidx;

    for (int it = 0; it < U; it++) {
        float bv = vals[0];
        int   bi = base;
#pragma unroll
        for (int r = 1; r < 8; r++) {
            if (vals[r] > bv) { bv = vals[r]; bi = base + r; }
        }
#pragma unroll
        for (int off = 1; off <= 32; off <<= 1) {
            float ov = __shfl_xor(bv, off);
            int   oi = __shfl_xor(bi, off);
            if (ov > bv || (ov == bv && oi < bi)) { bv = ov; bi = oi; }
        }
        int w = tid >> 6;
        if ((tid & 63) == 0) { wv[w] = bv; wi[w] = bi; }
        __syncthreads();
        if (tid == 0) {
            float Bv = wv[0]; int Bi = wi[0];
#pragma unroll
            for (int ww = 1; ww < 4; ww++) {
                if (wv[ww] > Bv || (wv[ww] == Bv && wi[ww] < Bi)) { Bv = wv[ww]; Bi = wi[ww]; }
            }
            Mtop[bh * U + it] = Bi;
            bidx = Bi;
        }
        __syncthreads();
        int kb = bidx;
#pragma unroll
        for (int r = 0; r < 8; r++) {
            if (base + r == kb) vals[r] = -INFINITY;
        }
    }
}

// ---------------------------------------------------------------------------
// K3a: per-chunk sums of v along L.  block = (b,h,c) XCD-swizzled, 64 thr.
// ---------------------------------------------------------------------------
__global__ void cumsum_part(const float* __restrict__ v, float* __restrict__ part) {
    int blk = blockIdx.x;          // [0, B*H*C)
    int xcd = blk & 7;
    int b   = xcd >> 1;
    int rr  = ((blk >> 3) << 1) | (xcd & 1);   // [0, H*C)
    int h  = rr >> 5;
    int c  = rr & 31;
    int d  = threadIdx.x;

    const float* base = v + ((size_t)(b * L + c * CHUNK) * H + h) * D + d;
    float s = 0.f;
    for (int i = 0; i < CHUNK; i++) s += base[(size_t)i * H * D];
    part[((size_t)(b * H + h) * C + c) * D + d] = s;
}

// ---------------------------------------------------------------------------
// K3b: prefix of chunk partials + in-chunk scan, write full output
// ---------------------------------------------------------------------------
__global__ void cumsum_write(const float* __restrict__ v,
                             const float* __restrict__ part,
                             float* __restrict__ out) {
    int blk = blockIdx.x;
    int xcd = blk & 7;
    int b   = xcd >> 1;
    int rr  = ((blk >> 3) << 1) | (xcd & 1);
    int h  = rr >> 5;
    int c  = rr & 31;
    int bh = b * H + h;
    int d  = threadIdx.x;

    float run = 0.f;
    for (int cc = 0; cc < c; cc++) run += part[((size_t)bh * C + cc) * D + d];

    const float* base  = v   + ((size_t)(b * L + c * CHUNK) * H + h) * D + d;
    float*       obase = out + ((size_t)(b * L + c * CHUNK) * H + h) * D + d;
    for (int i = 0; i < CHUNK; i++) {
        run += base[(size_t)i * H * D];
        obase[(size_t)i * H * D] = run;
    }
}

// ---------------------------------------------------------------------------
// K5a: batched-query segment attention.
// block = (b,h,seg) XCD-swizzled; 256 threads; all 40 selected queries of the
// (b,h) share one LDS-staged K/V tile of SEG=128 keys (40x logical-traffic cut
// vs per-query blocks). Score GEMM 40x128x64 + masked softmax partials + PV
// GEMM 40x64x128; writes {m,l} and unnormalized acc per (u,seg).
// ---------------------------------------------------------------------------
__global__ __launch_bounds__(256, 2)
void attn_batched(const float* __restrict__ q,
                  const float* __restrict__ k,
                  const float* __restrict__ v,
                  const int*   __restrict__ Mtop,
                  float* __restrict__ ml,
                  float* __restrict__ pacc) {
    int blk = blockIdx.x;              // [0, B*H*NSEG) = 512
    int xcd = blk & 7;
    int b   = xcd >> 1;
    int r   = ((blk >> 3) << 1) | (xcd & 1);   // [0, H*NSEG)
    int h   = r >> 4;
    int seg = r & 15;
    int bh  = b * H + h;
    int j0  = seg * SEG;
    int tid = threadIdx.x;

    __shared__ float Qs[U * D];        // 10.2 KB
    __shared__ float KV[SEG * D];      // 32.8 KB (K tile, then reused for V)
    __shared__ float Sc[U * SEG];      // 20.5 KB (slot-swizzled by u&15)
    __shared__ float red[U * 4];
    __shared__ float mrow[U];
    __shared__ int   qis[U];

    if (tid < U) qis[tid] = Mtop[bh * U + tid];
    __syncthreads();

    // stage Q rows (gathered) and K tile (coalesced 256B rows), XOR-swizzled
    for (int i = tid; i < U * 16; i += 256) {
        int u = i >> 4, d4 = i & 15;
        *(float4*)&Qs[u * D + d4 * 4] =
            *(const float4*)(q + ((size_t)(b * L + qis[u]) * H + h) * D + d4 * 4);
    }
    for (int i = tid; i < SEG * 16; i += 256) {
        int rr = i >> 4, d4 = i & 15;
        float4 kv = *(const float4*)(k + ((size_t)(b * L + j0 + rr) * H + h) * D + d4 * 4);
        *(float4*)&KV[rr * D + (d4 ^ (rr & 15)) * 4] = kv;
    }
    __syncthreads();

    // ---- score GEMM: thread tile 5u x 4j, K frags from swizzled LDS ----
    int ug = tid >> 5;        // 0..7   (u-group)
    int jg = tid & 31;        // 0..31  (j-group)
    int jlow = jg & 15;
    float acc[5][4];
#pragma unroll
    for (int uu = 0; uu < 5; uu++)
#pragma unroll
        for (int jj = 0; jj < 4; jj++) acc[uu][jj] = 0.f;

#pragma unroll
    for (int kk4 = 0; kk4 < 16; kk4++) {
        float4 kf[4];
        int slot = kk4 ^ jlow;         // (jg+32jj)&15 == jg&15
#pragma unroll
        for (int jj = 0; jj < 4; jj++)
            kf[jj] = *(const float4*)&KV[(jg + 32 * jj) * D + slot * 4];
#pragma unroll
        for (int uu = 0; uu < 5; uu++) {
            float4 qf = *(const float4*)&Qs[(ug * 5 + uu) * D + kk4 * 4];
#pragma unroll
            for (int jj = 0; jj < 4; jj++) {
                acc[uu][jj] += qf.x * kf[jj].x + qf.y * kf[jj].y
                             + qf.z * kf[jj].z + qf.w * kf[jj].w;
            }
        }
    }
    // write scaled scores; element j of row u lives at 4*((j>>2)^(u&15))+(j&3)
#pragma unroll
    for (int uu = 0; uu < 5; uu++) {
        int u = ug * 5 + uu;
        int um = u & 15;
#pragma unroll
        for (int jj = 0; jj < 4; jj++) {
            int j = jg + 32 * jj;
            Sc[u * SEG + 4 * ((j >> 2) ^ um) + (j & 3)] = acc[uu][jj] * 0.125f;
        }
    }
    __syncthreads();   // (A): Sc visible; all K reads done

    // stage V tile into KV (safe after A)
    for (int i = tid; i < SEG * 16; i += 256) {
        int rr = i >> 4, d4 = i & 15;
        float4 vv = *(const float4*)(v + ((size_t)(b * L + j0 + rr) * H + h) * D + d4 * 4);
        *(float4*)&KV[rr * D + (d4 ^ (rr & 15)) * 4] = vv;
    }

    // ---- masked softmax partials: thread (u, quarter), i = sq + 4t ----
    int su = tid >> 2, sq = tid & 3;
    int nkc = 0;
    if (tid < U * 4) {
        int nk = qis[su] + 1 - j0;
        nkc = nk < 0 ? 0 : (nk > SEG ? SEG : nk);
        int um = su & 15;
        float mv = -INFINITY;
        for (int t = 0; t < 32; t++) {
            int i = sq + 4 * t;
            if (i < nkc) mv = fmaxf(mv, Sc[su * SEG + 4 * ((i >> 2) ^ um) + (i & 3)]);
        }
        red[su * 4 + sq] = mv;
    }
    __syncthreads();   // (B): also covers V staging
    if (tid < U) {
        float m = fmaxf(fmaxf(red[tid * 4], red[tid * 4 + 1]),
                        fmaxf(red[tid * 4 + 2], red[tid * 4 + 3]));
        mrow[tid] = m;
    }
    __syncthreads();
    if (tid < U * 4) {
        float m = mrow[su];
        int um = su & 15;
        float ls = 0.f;
        for (int t = 0; t < 32; t++) {
            int i = sq + 4 * t;
            int addr = su * SEG + 4 * ((i >> 2) ^ um) + (i & 3);
            float e = 0.f;
            if (i < nkc) e = __expf(Sc[addr] - m);
            Sc[addr] = e;                 // masked / inactive -> 0
            ls += e;
        }
        red[su * 4 + sq] = ls;
    }
    __syncthreads();   // (C): e-matrix + sums ready
    if (tid < U) {
        float ls = (red[tid * 4] + red[tid * 4 + 1]) + (red[tid * 4 + 2] + red[tid * 4 + 3]);
        size_t mli = 2 * ((size_t)(bh * U + tid) * NSEG + seg);
        ml[mli]     = mrow[tid];
        ml[mli + 1] = ls;
    }

    // ---- PV GEMM: thread tile 5u x 2d; P reads are aligned b128 ----
    int vg = jg;               // d-pair group: d0 = 2*vg
    float a2[5][2];
#pragma unroll
    for (int uu = 0; uu < 5; uu++) { a2[uu][0] = 0.f; a2[uu][1] = 0.f; }

    for (int j4 = 0; j4 < 32; j4++) {
        float4 pf[5];
#pragma unroll
        for (int uu = 0; uu < 5; uu++) {
            int u = ug * 5 + uu;
            pf[uu] = *(const float4*)&Sc[u * SEG + 4 * (j4 ^ (u & 15))];
        }
#pragma unroll
        for (int jj = 0; jj < 4; jj++) {
            int j = j4 * 4 + jj;
            int fo = 4 * ((vg >> 1) ^ (j & 15)) + ((2 * vg) & 3);
            float2 vv = *(const float2*)&KV[j * D + fo];
#pragma unroll
            for (int uu = 0; uu < 5; uu++) {
                float p = ((const float*)&pf[uu])[jj];
                a2[uu][0] += p * vv.x;
                a2[uu][1] += p * vv.y;
            }
        }
    }
#pragma unroll
    for (int uu = 0; uu < 5; uu++) {
        int u = ug * 5 + uu;
        float2 w2 = make_float2(a2[uu][0], a2[uu][1]);
        *(float2*)&pacc[((size_t)(bh * U + u) * NSEG + seg) * D + 2 * vg] = w2;
    }
}

// ---------------------------------------------------------------------------
// K5b: combine NSEG partials per (b,h,u), write the output row.
// ---------------------------------------------------------------------------
__global__ void attn_combine(const int* __restrict__ Mtop,
                             const float* __restrict__ ml,
                             const float* __restrict__ pacc,
                             float* __restrict__ out) {
    int blk = blockIdx.x;          // bh*U + u
    int u  = blk % U;
    int bh = blk / U;
    int h  = bh % H;
    int b  = bh / H;
    int d  = threadIdx.x;
    int qi = Mtop[bh * U + u];

    size_t r0 = (size_t)blk * NSEG;
    float m = -INFINITY;
#pragma unroll
    for (int s = 0; s < NSEG; s++) m = fmaxf(m, ml[2 * (r0 + s)]);

    float lt = 0.f, acc = 0.f;
#pragma unroll
    for (int s = 0; s < NSEG; s++) {
        float ms = ml[2 * (r0 + s)];
        float w  = __expf(ms - m);          // -inf -> 0 (seg 0 always valid)
        lt  += ml[2 * (r0 + s) + 1] * w;
        acc += pacc[(r0 + s) * D + d] * w;
    }
    out[((size_t)(b * L + qi) * H + h) * D + d] = acc / lt;
}

// ---------------------------------------------------------------------------
extern "C" void kernel_launch(void* const* d_in, const int* in_sizes, int n_in,
                              void* d_out, int out_size, void* d_ws, size_t ws_size,
                              hipStream_t stream) {
    const float* q    = (const float*)d_in[0];
    const float* k    = (const float*)d_in[1];
    const float* v    = (const float*)d_in[2];
    const int*   samp = (const int*)d_in[3];
    float* out = (float*)d_out;

    // workspace layout
    float* M    = (float*)d_ws;                        // B*H*L
    int*   Mtop = (int*)(M + (size_t)B * H * L);       // B*H*U
    float* part = (float*)(Mtop + (size_t)B * H * U);  // B*H*C*D
    float* ml   = part + (size_t)B * H * C * D;        // B*H*U*NSEG*2
    float* pacc = ml + (size_t)B * H * U * NSEG * 2;   // B*H*U*NSEG*D

    compute_M<<<B * L, 256, 0, stream>>>(q, k, samp, M);
    topk_M<<<B * H, 256, 0, stream>>>(M, Mtop);
    cumsum_part<<<B * H * C, 64, 0, stream>>>(v, part);
    cumsum_write<<<B * H * C, 64, 0, stream>>>(v, part, out);
    attn_batched<<<B * H * NSEG, 256, 0, stream>>>(q, k, v, Mtop, ml, pacc);
    attn_combine<<<B * H * U, 64, 0, stream>>>(Mtop, ml, pacc, out);
}

// Round 5
// 186.960 us; speedup vs baseline: 2.5648x; 1.1683x over previous
//
#include <hip/hip_runtime.h>
#include <hip/hip_bf16.h>
#include <math.h>

// Problem constants (fixed by setup_inputs)
constexpr int B = 4;
constexpr int L = 2048;
constexpr int H = 8;
constexpr int D = 64;
constexpr int S = 40;   // sample_k
constexpr int U = 40;   // top-u queries
constexpr int C = 32;   // cumsum chunks
constexpr int CHUNK = L / C;   // 64
constexpr int NSEG = 16;       // key segments for attention
constexpr int SEG  = L / NSEG; // 128

// ---------------------------------------------------------------------------
// L1 fat kernel: blocks [0,256) = cumsum_part; blocks [256, 256+B*L) = compute_M.
//
// compute_M role: M[b,h,l] = max_s(q.k_samp) - sum_s(q.k_samp)/L.
//   256 thr = 8 h-groups x 32 lanes; per iter each h-group covers 2 samples
//   with float4/lane (16 B loads); partials to LDS (stride-17 pad, conflict
//   free); phase B: lane=sample serial sum + one 5-shfl reduce.
//   LDS 21.3 KB -> 7 blocks/CU (vs 40 KB/4 before).
// cumsum_part role: chunk sums of v. thread = (b,c,h,d), 64 strided adds.
// ---------------------------------------------------------------------------
__global__ void fused_Mpart(const float* __restrict__ q,
                            const float* __restrict__ k,
                            const float* __restrict__ v,
                            const int*   __restrict__ samp,
                            float* __restrict__ M,
                            float* __restrict__ part) {
    __shared__ float pa[H * 680];      // 8*40*17 floats = 21760 B
    int tid = threadIdx.x;

    if (blockIdx.x < 256) {
        // ---- cumsum_part ----
        int idx = blockIdx.x * 256 + tid;   // [0, B*C*H*D) = 65536
        int b   = idx >> 14;
        int rem = idx & 16383;
        int c   = rem >> 9;
        int hd  = rem & 511;
        const float* base = v + ((size_t)(b * L + c * CHUNK) * H * D) + hd;
        float s = 0.f;
        for (int i = 0; i < CHUNK; i++) s += base[(size_t)i * (H * D)];
        int h = hd >> 6, d = hd & 63;
        part[((size_t)(b * H + h) * C + c) * D + d] = s;
        return;
    }

    // ---- compute_M ----
    int blk = blockIdx.x - 256;        // [0, B*L)
    int xcd = blk & 7;
    int b   = xcd >> 1;
    int l   = ((blk >> 3) << 1) | (xcd & 1);
    int h      = tid >> 5;             // 0..7
    int lane32 = tid & 31;
    int g  = lane32 >> 4;              // sample sub-slot (0..1)
    int d4 = lane32 & 15;              // float4 index within row

    const float4 qv = *(const float4*)(q + ((size_t)(b * L + l) * H + h) * D + d4 * 4);
    const int* srow = samp + l * S;
    float* pah = pa + h * 680;

#pragma unroll 4
    for (int sb = 0; sb < S; sb += 2) {
        int i0 = srow[sb];
        int i1 = srow[sb + 1];
        int idx = g ? i1 : i0;
        int s = sb + g;
        float4 kv = *(const float4*)(k + ((size_t)(b * L + idx) * H + h) * D + d4 * 4);
        pah[s * 17 + d4] = qv.x * kv.x + qv.y * kv.y + qv.z * kv.z + qv.w * kv.w;
    }
    __syncthreads();

    // Phase B: lane s1 sums its sample's 16 partials (lanes 0..7 also s1+32)
    int s1 = lane32;
    float t0 = 0.f, t1 = 0.f, t2 = 0.f, t3 = 0.f;
#pragma unroll
    for (int i = 0; i < 16; i += 4) {
        t0 += pah[s1 * 17 + i];
        t1 += pah[s1 * 17 + i + 1];
        t2 += pah[s1 * 17 + i + 2];
        t3 += pah[s1 * 17 + i + 3];
    }
    float dot1 = (t0 + t1) + (t2 + t3);
    float mv = dot1, sv = dot1;
    if (lane32 < S - 32) {
        int s2 = 32 + lane32;
        float u0 = 0.f, u1 = 0.f, u2 = 0.f, u3 = 0.f;
#pragma unroll
        for (int i = 0; i < 16; i += 4) {
            u0 += pah[s2 * 17 + i];
            u1 += pah[s2 * 17 + i + 1];
            u2 += pah[s2 * 17 + i + 2];
            u3 += pah[s2 * 17 + i + 3];
        }
        float dot2 = (u0 + u1) + (u2 + u3);
        mv = fmaxf(mv, dot2);
        sv += dot2;
    }
#pragma unroll
    for (int off = 1; off <= 16; off <<= 1) {
        mv = fmaxf(mv, __shfl_xor(mv, off));
        sv += __shfl_xor(sv, off);
    }
    if (lane32 == 0) M[(size_t)(b * H + h) * L + l] = mv - sv * (1.0f / (float)L);
}

// ---------------------------------------------------------------------------
// L2 fat kernel: blocks [0,32) = topk_M; blocks [32, 32+256) = cumsum_write.
//
// topk_M: top-U of M per (b,h), tie -> lowest index. Register-resident with
//   cached local argmax (recompute only when the killed index hits our slots).
// cumsum_write: prefix of chunk partials + in-chunk scan, full output write.
// ---------------------------------------------------------------------------
__global__ void fused_topk_cumsum(const float* __restrict__ M,
                                  const float* __restrict__ v,
                                  const float* __restrict__ part,
                                  int* __restrict__ Mtop,
                                  float* __restrict__ out) {
    int tid = threadIdx.x;

    if (blockIdx.x >= 32) {
        // ---- cumsum_write ----
        int idx = (blockIdx.x - 32) * 256 + tid;  // [0, 65536)
        int b   = idx >> 14;
        int rem = idx & 16383;
        int c   = rem >> 9;                        // block-uniform
        int hd  = rem & 511;
        int h = hd >> 6, d = hd & 63;

        float run = 0.f;
        for (int cc = 0; cc < c; cc++)
            run += part[((size_t)(b * H + h) * C + cc) * D + d];

        const float* base  = v   + ((size_t)(b * L + c * CHUNK) * H * D) + hd;
        float*       obase = out + ((size_t)(b * L + c * CHUNK) * H * D) + hd;
        for (int i = 0; i < CHUNK; i++) {
            run += base[(size_t)i * (H * D)];
            obase[(size_t)i * (H * D)] = run;
        }
        return;
    }

    // ---- topk_M ----
    int bh = blockIdx.x;
    const float4* row4 = (const float4*)(M + (size_t)bh * L);
    float4 v0 = row4[tid * 2];
    float4 v1 = row4[tid * 2 + 1];
    float vals[8] = {v0.x, v0.y, v0.z, v0.w, v1.x, v1.y, v1.z, v1.w};
    int base = tid * 8;

    __shared__ float wv[4];
    __shared__ int   wi[4];
    __shared__ int   bidx;

    // initial local argmax (ascending idx: strict > keeps lowest index)
    float lbv = vals[0];
    int   lbi = base;
#pragma unroll
    for (int r = 1; r < 8; r++)
        if (vals[r] > lbv) { lbv = vals[r]; lbi = base + r; }

    for (int it = 0; it < U; it++) {
        float bv = lbv;
        int   bi = lbi;
#pragma unroll
        for (int off = 1; off <= 32; off <<= 1) {
            float ov = __shfl_xor(bv, off);
            int   oi = __shfl_xor(bi, off);
            if (ov > bv || (ov == bv && oi < bi)) { bv = ov; bi = oi; }
        }
        int w = tid >> 6;
        if ((tid & 63) == 0) { wv[w] = bv; wi[w] = bi; }
        __syncthreads();
        if (tid == 0) {
            float Bv = wv[0]; int Bi = wi[0];
#pragma unroll
            for (int ww = 1; ww < 4; ww++)
                if (wv[ww] > Bv || (wv[ww] == Bv && wi[ww] < Bi)) { Bv = wv[ww]; Bi = wi[ww]; }
            Mtop[bh * U + it] = Bi;
            bidx = Bi;
        }
        __syncthreads();
        int kb = bidx;
        if (kb >= base && kb < base + 8) {     // only the owner recomputes
#pragma unroll
            for (int r = 0; r < 8; r++)
                if (base + r == kb) vals[r] = -INFINITY;
            lbv = vals[0]; lbi = base;
#pragma unroll
            for (int r = 1; r < 8; r++)
                if (vals[r] > lbv) { lbv = vals[r]; lbi = base + r; }
        }
    }
}

// ---------------------------------------------------------------------------
// K5a: batched-query segment attention (unchanged from round 4).
// block = (b,h,seg) XCD-swizzled; 256 threads; all 40 selected queries of the
// (b,h) share one LDS-staged K/V tile of SEG=128 keys.
// ---------------------------------------------------------------------------
__global__ __launch_bounds__(256, 2)
void attn_batched(const float* __restrict__ q,
                  const float* __restrict__ k,
                  const float* __restrict__ v,
                  const int*   __restrict__ Mtop,
                  float* __restrict__ ml,
                  float* __restrict__ pacc) {
    int blk = blockIdx.x;              // [0, B*H*NSEG) = 512
    int xcd = blk & 7;
    int b   = xcd >> 1;
    int r   = ((blk >> 3) << 1) | (xcd & 1);   // [0, H*NSEG)
    int h   = r >> 4;
    int seg = r & 15;
    int bh  = b * H + h;
    int j0  = seg * SEG;
    int tid = threadIdx.x;

    __shared__ float Qs[U * D];        // 10.2 KB
    __shared__ float KV[SEG * D];      // 32.8 KB (K tile, then reused for V)
    __shared__ float Sc[U * SEG];      // 20.5 KB (slot-swizzled by u&15)
    __shared__ float red[U * 4];
    __shared__ float mrow[U];
    __shared__ int   qis[U];

    if (tid < U) qis[tid] = Mtop[bh * U + tid];
    __syncthreads();

    for (int i = tid; i < U * 16; i += 256) {
        int u = i >> 4, d4 = i & 15;
        *(float4*)&Qs[u * D + d4 * 4] =
            *(const float4*)(q + ((size_t)(b * L + qis[u]) * H + h) * D + d4 * 4);
    }
    for (int i = tid; i < SEG * 16; i += 256) {
        int rr = i >> 4, d4 = i & 15;
        float4 kv = *(const float4*)(k + ((size_t)(b * L + j0 + rr) * H + h) * D + d4 * 4);
        *(float4*)&KV[rr * D + (d4 ^ (rr & 15)) * 4] = kv;
    }
    __syncthreads();

    // ---- score GEMM: thread tile 5u x 4j ----
    int ug = tid >> 5;        // 0..7
    int jg = tid & 31;        // 0..31
    int jlow = jg & 15;
    float acc[5][4];
#pragma unroll
    for (int uu = 0; uu < 5; uu++)
#pragma unroll
        for (int jj = 0; jj < 4; jj++) acc[uu][jj] = 0.f;

#pragma unroll
    for (int kk4 = 0; kk4 < 16; kk4++) {
        float4 kf[4];
        int slot = kk4 ^ jlow;
#pragma unroll
        for (int jj = 0; jj < 4; jj++)
            kf[jj] = *(const float4*)&KV[(jg + 32 * jj) * D + slot * 4];
#pragma unroll
        for (int uu = 0; uu < 5; uu++) {
            float4 qf = *(const float4*)&Qs[(ug * 5 + uu) * D + kk4 * 4];
#pragma unroll
            for (int jj = 0; jj < 4; jj++) {
                acc[uu][jj] += qf.x * kf[jj].x + qf.y * kf[jj].y
                             + qf.z * kf[jj].z + qf.w * kf[jj].w;
            }
        }
    }
#pragma unroll
    for (int uu = 0; uu < 5; uu++) {
        int u = ug * 5 + uu;
        int um = u & 15;
#pragma unroll
        for (int jj = 0; jj < 4; jj++) {
            int j = jg + 32 * jj;
            Sc[u * SEG + 4 * ((j >> 2) ^ um) + (j & 3)] = acc[uu][jj] * 0.125f;
        }
    }
    __syncthreads();   // (A): Sc visible; all K reads done

    // stage V tile into KV
    for (int i = tid; i < SEG * 16; i += 256) {
        int rr = i >> 4, d4 = i & 15;
        float4 vv = *(const float4*)(v + ((size_t)(b * L + j0 + rr) * H + h) * D + d4 * 4);
        *(float4*)&KV[rr * D + (d4 ^ (rr & 15)) * 4] = vv;
    }

    // ---- masked softmax partials ----
    int su = tid >> 2, sq = tid & 3;
    int nkc = 0;
    if (tid < U * 4) {
        int nk = qis[su] + 1 - j0;
        nkc = nk < 0 ? 0 : (nk > SEG ? SEG : nk);
        int um = su & 15;
        float mvx = -INFINITY;
        for (int t = 0; t < 32; t++) {
            int i = sq + 4 * t;
            if (i < nkc) mvx = fmaxf(mvx, Sc[su * SEG + 4 * ((i >> 2) ^ um) + (i & 3)]);
        }
        red[su * 4 + sq] = mvx;
    }
    __syncthreads();   // (B): also covers V staging
    if (tid < U) {
        float m = fmaxf(fmaxf(red[tid * 4], red[tid * 4 + 1]),
                        fmaxf(red[tid * 4 + 2], red[tid * 4 + 3]));
        mrow[tid] = m;
    }
    __syncthreads();
    if (tid < U * 4) {
        float m = mrow[su];
        int um = su & 15;
        float ls = 0.f;
        for (int t = 0; t < 32; t++) {
            int i = sq + 4 * t;
            int addr = su * SEG + 4 * ((i >> 2) ^ um) + (i & 3);
            float e = 0.f;
            if (i < nkc) e = __expf(Sc[addr] - m);
            Sc[addr] = e;
            ls += e;
        }
        red[su * 4 + sq] = ls;
    }
    __syncthreads();   // (C)
    if (tid < U) {
        float ls = (red[tid * 4] + red[tid * 4 + 1]) + (red[tid * 4 + 2] + red[tid * 4 + 3]);
        size_t mli = 2 * ((size_t)(bh * U + tid) * NSEG + seg);
        ml[mli]     = mrow[tid];
        ml[mli + 1] = ls;
    }

    // ---- PV GEMM: thread tile 5u x 2d ----
    int vg = jg;
    float a2[5][2];
#pragma unroll
    for (int uu = 0; uu < 5; uu++) { a2[uu][0] = 0.f; a2[uu][1] = 0.f; }

    for (int j4 = 0; j4 < 32; j4++) {
        float4 pf[5];
#pragma unroll
        for (int uu = 0; uu < 5; uu++) {
            int u = ug * 5 + uu;
            pf[uu] = *(const float4*)&Sc[u * SEG + 4 * (j4 ^ (u & 15))];
        }
#pragma unroll
        for (int jj = 0; jj < 4; jj++) {
            int j = j4 * 4 + jj;
            int fo = 4 * ((vg >> 1) ^ (j & 15)) + ((2 * vg) & 3);
            float2 vv = *(const float2*)&KV[j * D + fo];
#pragma unroll
            for (int uu = 0; uu < 5; uu++) {
                float p = ((const float*)&pf[uu])[jj];
                a2[uu][0] += p * vv.x;
                a2[uu][1] += p * vv.y;
            }
        }
    }
#pragma unroll
    for (int uu = 0; uu < 5; uu++) {
        int u = ug * 5 + uu;
        float2 w2 = make_float2(a2[uu][0], a2[uu][1]);
        *(float2*)&pacc[((size_t)(bh * U + u) * NSEG + seg) * D + 2 * vg] = w2;
    }
}

// ---------------------------------------------------------------------------
// K5b: combine NSEG partials per (b,h,u), write the output row.
// ---------------------------------------------------------------------------
__global__ void attn_combine(const int* __restrict__ Mtop,
                             const float* __restrict__ ml,
                             const float* __restrict__ pacc,
                             float* __restrict__ out) {
    int blk = blockIdx.x;          // bh*U + u
    int u  = blk % U;
    int bh = blk / U;
    int h  = bh % H;
    int b  = bh / H;
    int d  = threadIdx.x;
    int qi = Mtop[bh * U + u];

    size_t r0 = (size_t)blk * NSEG;
    float m = -INFINITY;
#pragma unroll
    for (int s = 0; s < NSEG; s++) m = fmaxf(m, ml[2 * (r0 + s)]);

    float lt = 0.f, acc = 0.f;
#pragma unroll
    for (int s = 0; s < NSEG; s++) {
        float ms = ml[2 * (r0 + s)];
        float w  = __expf(ms - m);
        lt  += ml[2 * (r0 + s) + 1] * w;
        acc += pacc[(r0 + s) * D + d] * w;
    }
    out[((size_t)(b * L + qi) * H + h) * D + d] = acc / lt;
}

// ---------------------------------------------------------------------------
extern "C" void kernel_launch(void* const* d_in, const int* in_sizes, int n_in,
                              void* d_out, int out_size, void* d_ws, size_t ws_size,
                              hipStream_t stream) {
    const float* q    = (const float*)d_in[0];
    const float* k    = (const float*)d_in[1];
    const float* v    = (const float*)d_in[2];
    const int*   samp = (const int*)d_in[3];
    float* out = (float*)d_out;

    // workspace layout
    float* M    = (float*)d_ws;                        // B*H*L
    int*   Mtop = (int*)(M + (size_t)B * H * L);       // B*H*U
    float* part = (float*)(Mtop + (size_t)B * H * U);  // B*H*C*D
    float* ml   = part + (size_t)B * H * C * D;        // B*H*U*NSEG*2
    float* pacc = ml + (size_t)B * H * U * NSEG * 2;   // B*H*U*NSEG*D

    fused_Mpart<<<256 + B * L, 256, 0, stream>>>(q, k, v, samp, M, part);
    fused_topk_cumsum<<<32 + 256, 256, 0, stream>>>(M, v, part, Mtop, out);
    attn_batched<<<B * H * NSEG, 256, 0, stream>>>(q, k, v, Mtop, ml, pacc);
    attn_combine<<<B * H * U, 64, 0, stream>>>(Mtop, ml, pacc, out);
}

// Round 6
// 184.151 us; speedup vs baseline: 2.6039x; 1.0153x over previous
//
#include <hip/hip_runtime.h>
#include <hip/hip_bf16.h>
#include <math.h>

// Problem constants (fixed by setup_inputs)
constexpr int B = 4;
constexpr int L = 2048;
constexpr int H = 8;
constexpr int D = 64;
constexpr int S = 40;   // sample_k
constexpr int U = 40;   // top-u queries
constexpr int C = 32;   // cumsum chunks
constexpr int CHUNK = L / C;   // 64
constexpr int NSEG = 16;       // key segments for attention
constexpr int SEG  = L / NSEG; // 128
constexpr int PAH  = 688;      // per-h LDS stride (688 % 32 == 16 -> <=2-way banks)

// ---------------------------------------------------------------------------
// L1 fat kernel: blocks [0,256) = cumsum_part; blocks [256, 256+B*L) = compute_M.
// compute_M: 256 thr = 8 h-groups x 32 lanes; 2 samples/h-group/iter with
// float4/lane; partials to LDS (stride-17 in-sample, 688 per-h: conflict-free);
// phase B: lane=sample serial sum + one 5-shfl reduce.
// ---------------------------------------------------------------------------
__global__ void fused_Mpart(const float* __restrict__ q,
                            const float* __restrict__ k,
                            const float* __restrict__ v,
                            const int*   __restrict__ samp,
                            float* __restrict__ M,
                            float* __restrict__ part) {
    __shared__ float pa[H * PAH];      // 8*688*4 = 22016 B
    int tid = threadIdx.x;

    if (blockIdx.x < 256) {
        // ---- cumsum_part ----
        int idx = blockIdx.x * 256 + tid;   // [0, B*C*H*D) = 65536
        int b   = idx >> 14;
        int rem = idx & 16383;
        int c   = rem >> 9;
        int hd  = rem & 511;
        const float* base = v + ((size_t)(b * L + c * CHUNK) * H * D) + hd;
        float s = 0.f;
        for (int i = 0; i < CHUNK; i++) s += base[(size_t)i * (H * D)];
        int h = hd >> 6, d = hd & 63;
        part[((size_t)(b * H + h) * C + c) * D + d] = s;
        return;
    }

    // ---- compute_M ----
    int blk = blockIdx.x - 256;        // [0, B*L)
    int xcd = blk & 7;
    int b   = xcd >> 1;
    int l   = ((blk >> 3) << 1) | (xcd & 1);
    int h      = tid >> 5;             // 0..7
    int lane32 = tid & 31;
    int g  = lane32 >> 4;              // sample sub-slot (0..1)
    int d4 = lane32 & 15;              // float4 index within row

    const float4 qv = *(const float4*)(q + ((size_t)(b * L + l) * H + h) * D + d4 * 4);
    const int* srow = samp + l * S;
    float* pah = pa + h * PAH;

#pragma unroll 10
    for (int sb = 0; sb < S; sb += 2) {
        int i0 = srow[sb];
        int i1 = srow[sb + 1];
        int idx = g ? i1 : i0;
        int s = sb + g;
        float4 kv = *(const float4*)(k + ((size_t)(b * L + idx) * H + h) * D + d4 * 4);
        pah[s * 17 + d4] = qv.x * kv.x + qv.y * kv.y + qv.z * kv.z + qv.w * kv.w;
    }
    __syncthreads();

    // Phase B: lane s1 sums its sample's 16 partials (lanes 0..7 also s1+32)
    int s1 = lane32;
    float t0 = 0.f, t1 = 0.f, t2 = 0.f, t3 = 0.f;
#pragma unroll
    for (int i = 0; i < 16; i += 4) {
        t0 += pah[s1 * 17 + i];
        t1 += pah[s1 * 17 + i + 1];
        t2 += pah[s1 * 17 + i + 2];
        t3 += pah[s1 * 17 + i + 3];
    }
    float dot1 = (t0 + t1) + (t2 + t3);
    float mv = dot1, sv = dot1;
    if (lane32 < S - 32) {
        int s2 = 32 + lane32;
        float u0 = 0.f, u1 = 0.f, u2 = 0.f, u3 = 0.f;
#pragma unroll
        for (int i = 0; i < 16; i += 4) {
            u0 += pah[s2 * 17 + i];
            u1 += pah[s2 * 17 + i + 1];
            u2 += pah[s2 * 17 + i + 2];
            u3 += pah[s2 * 17 + i + 3];
        }
        float dot2 = (u0 + u1) + (u2 + u3);
        mv = fmaxf(mv, dot2);
        sv += dot2;
    }
#pragma unroll
    for (int off = 1; off <= 16; off <<= 1) {
        mv = fmaxf(mv, __shfl_xor(mv, off));
        sv += __shfl_xor(sv, off);
    }
    if (lane32 == 0) M[(size_t)(b * H + h) * L + l] = mv - sv * (1.0f / (float)L);
}

// ---------------------------------------------------------------------------
// L2 fat kernel, 64 threads/block.
// blocks [0,32): topk — ONE WAVE per (b,h), 32 values/lane in registers as
//   sortable-u32; per round extract the global TOP-2 via a 6-level u64
//   butterfly of per-lane sorted pairs (key = sortable<<32 | ~idx: max = value
//   order, tie -> lowest index). 20 rounds, no barriers, no dynamic indexing.
// blocks [32, 32+1024): cumsum_write (prefix of chunk partials + in-chunk scan).
// ---------------------------------------------------------------------------
__global__ void fused_topk_cumsum(const float* __restrict__ M,
                                  const float* __restrict__ v,
                                  const float* __restrict__ part,
                                  int* __restrict__ Mtop,
                                  float* __restrict__ out) {
    int tid = threadIdx.x;   // 0..63

    if (blockIdx.x >= 32) {
        // ---- cumsum_write ----
        int idx = (blockIdx.x - 32) * 64 + tid;   // [0, 65536)
        int b   = idx >> 14;
        int rem = idx & 16383;
        int c   = rem >> 9;                        // block-uniform
        int hd  = rem & 511;
        int h = hd >> 6, d = hd & 63;              // h block-uniform

        float run = 0.f;
        for (int cc = 0; cc < c; cc++)
            run += part[((size_t)(b * H + h) * C + cc) * D + d];

        const float* base  = v   + ((size_t)(b * L + c * CHUNK) * H * D) + hd;
        float*       obase = out + ((size_t)(b * L + c * CHUNK) * H * D) + hd;
        for (int i = 0; i < CHUNK; i++) {
            run += base[(size_t)i * (H * D)];
            obase[(size_t)i * (H * D)] = run;
        }
        return;
    }

    // ---- topk ----
    int bh   = blockIdx.x;
    int base = tid * 32;
    const float* row = M + (size_t)bh * L;

    unsigned int vals[32];                    // sortable-u32 per element
#pragma unroll
    for (int r4 = 0; r4 < 8; r4++) {
        float4 f = *(const float4*)(row + base + r4 * 4);
        const float ff[4] = {f.x, f.y, f.z, f.w};
#pragma unroll
        for (int j = 0; j < 4; j++) {
            unsigned int i = __float_as_uint(ff[j]);
            vals[r4 * 4 + j] = (i & 0x80000000u) ? ~i : (i | 0x80000000u);
        }
    }

    // local sorted top-2 (keys: 0 == killed/none, real keys > 2^32)
    unsigned long long k1 = 0ull, k2 = 0ull;
#pragma unroll
    for (int r = 0; r < 32; r++) {
        unsigned long long kk =
            ((unsigned long long)vals[r] << 32) | (unsigned int)~(base + r);
        if (kk > k1) { k2 = k1; k1 = kk; }
        else if (kk > k2) { k2 = kk; }
    }

    for (int it = 0; it < U; it += 2) {
        unsigned long long a1 = k1, a2 = k2;
#pragma unroll
        for (int off = 1; off < 64; off <<= 1) {
            unsigned long long o1 = __shfl_xor(a1, off);
            unsigned long long o2 = __shfl_xor(a2, off);
            unsigned long long hi = a1 > o1 ? a1 : o1;
            unsigned long long lo = a1 > o1 ? o1 : a1;
            unsigned long long ss = a2 > o2 ? a2 : o2;
            a1 = hi;
            a2 = lo > ss ? lo : ss;
        }
        int i1 = (int)~(unsigned int)a1;      // global row index of max
        int i2 = (int)~(unsigned int)a2;      // ... of 2nd max
        if (tid == 0) {
            Mtop[bh * U + it]     = i1;
            Mtop[bh * U + it + 1] = i2;
        }
        bool own1 = (i1 >> 5) == tid;
        bool own2 = (i2 >> 5) == tid;
        if (own1 | own2) {
            int r1 = own1 ? (i1 & 31) : 32;
            int r2 = own2 ? (i2 & 31) : 32;
#pragma unroll
            for (int r = 0; r < 32; r++)
                if (r == r1 || r == r2) vals[r] = 0u;
            k1 = 0ull; k2 = 0ull;
#pragma unroll
            for (int r = 0; r < 32; r++) {
                unsigned long long kk =
                    ((unsigned long long)vals[r] << 32) | (unsigned int)~(base + r);
                if (kk > k1) { k2 = k1; k1 = kk; }
                else if (kk > k2) { k2 = kk; }
            }
        }
    }
}

// ---------------------------------------------------------------------------
// K5a: batched-query segment attention (unchanged).
// block = (b,h,seg) XCD-swizzled; 256 threads; 40 queries share one LDS K/V
// tile of SEG=128 keys.
// ---------------------------------------------------------------------------
__global__ __launch_bounds__(256, 2)
void attn_batched(const float* __restrict__ q,
                  const float* __restrict__ k,
                  const float* __restrict__ v,
                  const int*   __restrict__ Mtop,
                  float* __restrict__ ml,
                  float* __restrict__ pacc) {
    int blk = blockIdx.x;              // [0, B*H*NSEG) = 512
    int xcd = blk & 7;
    int b   = xcd >> 1;
    int r   = ((blk >> 3) << 1) | (xcd & 1);   // [0, H*NSEG)
    int h   = r >> 4;
    int seg = r & 15;
    int bh  = b * H + h;
    int j0  = seg * SEG;
    int tid = threadIdx.x;

    __shared__ float Qs[U * D];        // 10.2 KB
    __shared__ float KV[SEG * D];      // 32.8 KB (K tile, then reused for V)
    __shared__ float Sc[U * SEG];      // 20.5 KB (slot-swizzled by u&15)
    __shared__ float red[U * 4];
    __shared__ float mrow[U];
    __shared__ int   qis[U];

    if (tid < U) qis[tid] = Mtop[bh * U + tid];
    __syncthreads();

    for (int i = tid; i < U * 16; i += 256) {
        int u = i >> 4, d4 = i & 15;
        *(float4*)&Qs[u * D + d4 * 4] =
            *(const float4*)(q + ((size_t)(b * L + qis[u]) * H + h) * D + d4 * 4);
    }
    for (int i = tid; i < SEG * 16; i += 256) {
        int rr = i >> 4, d4 = i & 15;
        float4 kv = *(const float4*)(k + ((size_t)(b * L + j0 + rr) * H + h) * D + d4 * 4);
        *(float4*)&KV[rr * D + (d4 ^ (rr & 15)) * 4] = kv;
    }
    __syncthreads();

    // ---- score GEMM: thread tile 5u x 4j ----
    int ug = tid >> 5;        // 0..7
    int jg = tid & 31;        // 0..31
    int jlow = jg & 15;
    float acc[5][4];
#pragma unroll
    for (int uu = 0; uu < 5; uu++)
#pragma unroll
        for (int jj = 0; jj < 4; jj++) acc[uu][jj] = 0.f;

#pragma unroll
    for (int kk4 = 0; kk4 < 16; kk4++) {
        float4 kf[4];
        int slot = kk4 ^ jlow;
#pragma unroll
        for (int jj = 0; jj < 4; jj++)
            kf[jj] = *(const float4*)&KV[(jg + 32 * jj) * D + slot * 4];
#pragma unroll
        for (int uu = 0; uu < 5; uu++) {
            float4 qf = *(const float4*)&Qs[(ug * 5 + uu) * D + kk4 * 4];
#pragma unroll
            for (int jj = 0; jj < 4; jj++) {
                acc[uu][jj] += qf.x * kf[jj].x + qf.y * kf[jj].y
                             + qf.z * kf[jj].z + qf.w * kf[jj].w;
            }
        }
    }
#pragma unroll
    for (int uu = 0; uu < 5; uu++) {
        int u = ug * 5 + uu;
        int um = u & 15;
#pragma unroll
        for (int jj = 0; jj < 4; jj++) {
            int j = jg + 32 * jj;
            Sc[u * SEG + 4 * ((j >> 2) ^ um) + (j & 3)] = acc[uu][jj] * 0.125f;
        }
    }
    __syncthreads();   // (A): Sc visible; all K reads done

    // stage V tile into KV
    for (int i = tid; i < SEG * 16; i += 256) {
        int rr = i >> 4, d4 = i & 15;
        float4 vv = *(const float4*)(v + ((size_t)(b * L + j0 + rr) * H + h) * D + d4 * 4);
        *(float4*)&KV[rr * D + (d4 ^ (rr & 15)) * 4] = vv;
    }

    // ---- masked softmax partials ----
    int su = tid >> 2, sq = tid & 3;
    int nkc = 0;
    if (tid < U * 4) {
        int nk = qis[su] + 1 - j0;
        nkc = nk < 0 ? 0 : (nk > SEG ? SEG : nk);
        int um = su & 15;
        float mvx = -INFINITY;
        for (int t = 0; t < 32; t++) {
            int i = sq + 4 * t;
            if (i < nkc) mvx = fmaxf(mvx, Sc[su * SEG + 4 * ((i >> 2) ^ um) + (i & 3)]);
        }
        red[su * 4 + sq] = mvx;
    }
    __syncthreads();   // (B): also covers V staging
    if (tid < U) {
        float m = fmaxf(fmaxf(red[tid * 4], red[tid * 4 + 1]),
                        fmaxf(red[tid * 4 + 2], red[tid * 4 + 3]));
        mrow[tid] = m;
    }
    __syncthreads();
    if (tid < U * 4) {
        float m = mrow[su];
        int um = su & 15;
        float ls = 0.f;
        for (int t = 0; t < 32; t++) {
            int i = sq + 4 * t;
            int addr = su * SEG + 4 * ((i >> 2) ^ um) + (i & 3);
            float e = 0.f;
            if (i < nkc) e = __expf(Sc[addr] - m);
            Sc[addr] = e;
            ls += e;
        }
        red[su * 4 + sq] = ls;
    }
    __syncthreads();   // (C)
    if (tid < U) {
        float ls = (red[tid * 4] + red[tid * 4 + 1]) + (red[tid * 4 + 2] + red[tid * 4 + 3]);
        size_t mli = 2 * ((size_t)(bh * U + tid) * NSEG + seg);
        ml[mli]     = mrow[tid];
        ml[mli + 1] = ls;
    }

    // ---- PV GEMM: thread tile 5u x 2d ----
    int vg = jg;
    float a2[5][2];
#pragma unroll
    for (int uu = 0; uu < 5; uu++) { a2[uu][0] = 0.f; a2[uu][1] = 0.f; }

    for (int j4 = 0; j4 < 32; j4++) {
        float4 pf[5];
#pragma unroll
        for (int uu = 0; uu < 5; uu++) {
            int u = ug * 5 + uu;
            pf[uu] = *(const float4*)&Sc[u * SEG + 4 * (j4 ^ (u & 15))];
        }
#pragma unroll
        for (int jj = 0; jj < 4; jj++) {
            int j = j4 * 4 + jj;
            int fo = 4 * ((vg >> 1) ^ (j & 15)) + ((2 * vg) & 3);
            float2 vv = *(const float2*)&KV[j * D + fo];
#pragma unroll
            for (int uu = 0; uu < 5; uu++) {
                float p = ((const float*)&pf[uu])[jj];
                a2[uu][0] += p * vv.x;
                a2[uu][1] += p * vv.y;
            }
        }
    }
#pragma unroll
    for (int uu = 0; uu < 5; uu++) {
        int u = ug * 5 + uu;
        float2 w2 = make_float2(a2[uu][0], a2[uu][1]);
        *(float2*)&pacc[((size_t)(bh * U + u) * NSEG + seg) * D + 2 * vg] = w2;
    }
}

// ---------------------------------------------------------------------------
// K5b: combine NSEG partials per (b,h,u), write the output row.
// ---------------------------------------------------------------------------
__global__ void attn_combine(const int* __restrict__ Mtop,
                             const float* __restrict__ ml,
                             const float* __restrict__ pacc,
                             float* __restrict__ out) {
    int blk = blockIdx.x;          // bh*U + u
    int u  = blk % U;
    int bh = blk / U;
    int h  = bh % H;
    int b  = bh / H;
    int d  = threadIdx.x;
    int qi = Mtop[bh * U + u];

    size_t r0 = (size_t)blk * NSEG;
    float m = -INFINITY;
#pragma unroll
    for (int s = 0; s < NSEG; s++) m = fmaxf(m, ml[2 * (r0 + s)]);

    float lt = 0.f, acc = 0.f;
#pragma unroll
    for (int s = 0; s < NSEG; s++) {
        float ms = ml[2 * (r0 + s)];
        float w  = __expf(ms - m);
        lt  += ml[2 * (r0 + s) + 1] * w;
        acc += pacc[(r0 + s) * D + d] * w;
    }
    out[((size_t)(b * L + qi) * H + h) * D + d] = acc / lt;
}

// ---------------------------------------------------------------------------
extern "C" void kernel_launch(void* const* d_in, const int* in_sizes, int n_in,
                              void* d_out, int out_size, void* d_ws, size_t ws_size,
                              hipStream_t stream) {
    const float* q    = (const float*)d_in[0];
    const float* k    = (const float*)d_in[1];
    const float* v    = (const float*)d_in[2];
    const int*   samp = (const int*)d_in[3];
    float* out = (float*)d_out;

    // workspace layout
    float* M    = (float*)d_ws;                        // B*H*L
    int*   Mtop = (int*)(M + (size_t)B * H * L);       // B*H*U
    float* part = (float*)(Mtop + (size_t)B * H * U);  // B*H*C*D
    float* ml   = part + (size_t)B * H * C * D;        // B*H*U*NSEG*2
    float* pacc = ml + (size_t)B * H * U * NSEG * 2;   // B*H*U*NSEG*D

    fused_Mpart<<<256 + B * L, 256, 0, stream>>>(q, k, v, samp, M, part);
    fused_topk_cumsum<<<32 + 1024, 64, 0, stream>>>(M, v, part, Mtop, out);
    attn_batched<<<B * H * NSEG, 256, 0, stream>>>(q, k, v, Mtop, ml, pacc);
    attn_combine<<<B * H * U, 64, 0, stream>>>(Mtop, ml, pacc, out);
}